// Round 3
// baseline (605.820 us; speedup 1.0000x reference)
//
#include <hip/hip_runtime.h>
#include <hip/hip_bf16.h>

#define N_TOK 8192
#define DDIM 1024
#define HDIM 4096
#define NEXP 8
#define TOPK 2
#define NK (N_TOK*TOPK)
#define BM 256
#define BK 64
#define MAXT 72    // 16384/256 + 8 pad tiles

typedef __hip_bfloat16 bf16;
typedef __attribute__((ext_vector_type(8))) short bf16x8;
typedef __attribute__((ext_vector_type(4))) float f32x4;

__device__ __forceinline__ void gload16(const void* g, void* lds) {
  auto l = (__attribute__((address_space(3))) unsigned int*)(unsigned int)(unsigned long long)lds;
  auto gg = (const __attribute__((address_space(1))) unsigned int*)(unsigned long long)g;
  __builtin_amdgcn_global_load_lds(gg, l, 16, 0, 0);
}

// ---- router ----
__global__ void k_detect(const int* __restrict__ idx, int* __restrict__ flag) {
  if (threadIdx.x == 0 && blockIdx.x == 0) {
    int allz = 1;
    for (int i = 1; i < 32; i += 2) allz &= (idx[i] == 0);
    *flag = allz ? 2 : 1;   // 2 => int64 little-endian, 1 => int32
  }
}

__global__ void k_count(const int* __restrict__ idx, const int* __restrict__ flag,
                        int* __restrict__ cnt) {
  int r = blockIdx.x * blockDim.x + threadIdx.x;
  if (r >= NK) return;
  int s = *flag;
  int e = idx[r * s];
  e = min(max(e, 0), NEXP - 1);
  atomicAdd(&cnt[e], 1);
}

__global__ void k_scan(const int* __restrict__ cnt, int* __restrict__ offp,
                       int* __restrict__ off2, int* __restrict__ texp,
                       int* __restrict__ tok) {
  __shared__ int so[NEXP + 1], sc[NEXP];
  int tid = threadIdx.x;
  if (tid == 0) {
    int cum = 0;
    for (int e = 0; e < NEXP; e++) {
      so[e] = cum; sc[e] = cnt[e];
      cum += ((cnt[e] + BM - 1) / BM) * BM;
    }
    so[NEXP] = cum;
    for (int e = 0; e <= NEXP; e++) offp[e] = so[e];
  }
  __syncthreads();
  if (tid < NEXP) off2[tid] = so[tid];
  int total_tiles = so[NEXP] / BM;
  for (int t = tid; t < MAXT; t += blockDim.x) {
    int e = -1;
    if (t < total_tiles) {
      for (int q = 0; q < NEXP; q++)
        if (t * BM >= so[q] && t * BM < so[q + 1]) e = q;
    }
    texp[t] = e;
  }
  for (int e = 0; e < NEXP; e++) {
    int start = so[e] + sc[e], end = so[e + 1];
    for (int i = start + tid; i < end; i += blockDim.x) tok[i] = 0;
  }
}

__global__ void k_scatter(const int* __restrict__ idx, const int* __restrict__ flag,
                          int* __restrict__ off2, int* __restrict__ tok,
                          int* __restrict__ pos) {
  int r = blockIdx.x * blockDim.x + threadIdx.x;
  if (r >= NK) return;
  int s = *flag;
  int e = idx[r * s];
  e = min(max(e, 0), NEXP - 1);
  int p = atomicAdd(&off2[e], 1);
  tok[p] = r >> 1;
  pos[r] = p;
}

// ---- converts ----
__global__ void k_cvt_x(const float* __restrict__ x, bf16* __restrict__ xb) {
  int i = blockIdx.x * blockDim.x + threadIdx.x;   // over N*D/8
  if (i >= N_TOK * DDIM / 8) return;
  float4 a = ((const float4*)x)[(size_t)i * 2];
  float4 b = ((const float4*)x)[(size_t)i * 2 + 1];
  union { bf16 h[8]; uint4 v; } u;
  u.h[0] = __float2bfloat16(a.x); u.h[1] = __float2bfloat16(a.y);
  u.h[2] = __float2bfloat16(a.z); u.h[3] = __float2bfloat16(a.w);
  u.h[4] = __float2bfloat16(b.x); u.h[5] = __float2bfloat16(b.y);
  u.h[6] = __float2bfloat16(b.z); u.h[7] = __float2bfloat16(b.w);
  *(uint4*)&xb[(size_t)i * 8] = u.v;
}

// [E][R][C] fp32 -> [E][C][R] bf16, ushort2 stores
__global__ void k_transpose(const float* __restrict__ in, bf16* __restrict__ out,
                            int R, int C) {
  __shared__ float t[32][33];
  size_t ebase = (size_t)blockIdx.z * R * C;
  int tx = threadIdx.x & 31, ty = threadIdx.x >> 5;
  int c0 = blockIdx.x * 32, r0 = blockIdx.y * 32;
#pragma unroll
  for (int j = 0; j < 4; j++)
    t[ty + j * 8][tx] = in[ebase + (size_t)(r0 + ty + j * 8) * C + c0 + tx];
  __syncthreads();
  int tx2 = (threadIdx.x & 15) * 2;
  int cy  = threadIdx.x >> 4;
#pragma unroll
  for (int p = 0; p < 2; p++) {
    int c = cy + p * 16;
    union { bf16 h[2]; unsigned int u; } w;
    w.h[0] = __float2bfloat16(t[tx2][c]);
    w.h[1] = __float2bfloat16(t[tx2 + 1][c]);
    *(unsigned int*)&out[ebase + (size_t)(c0 + c) * R + r0 + tx2] = w.u;
  }
}

// ---- grouped GEMM, 8-phase counted-vmcnt schedule (m201 port) ----
// MODE 0: X(gathered) @ W1t -> hbuf bf16 (+bias, ReLU). 256x256 tile, 128x64/wave.
// MODE 1: hbuf @ W2t -> ybuf bf16 (+bias).             256x128 tile,  64x64/wave.
template<int MODE>
__global__ __launch_bounds__(512, 2) void k_gemm(
    const bf16* __restrict__ A, const bf16* __restrict__ Bt,
    const float* __restrict__ bias, const int* __restrict__ texp,
    const int* __restrict__ tok, int tile_base, void* __restrict__ Cout)
{
  constexpr int KT    = MODE ? HDIM : DDIM;
  constexpr int NCOL  = MODE ? DDIM : HDIM;
  constexpr int BNT   = MODE ? 128 : 256;
  constexpr int GX    = NCOL / BNT;          // 8 or 16
  constexpr int MI    = MODE ? 4 : 8;        // 16-row frags per wave
  constexpr int MPP   = MI / 4;              // mi per phase (1 or 2)
  constexpr int NT    = KT / BK;             // 64 or 16
  constexpr int NITER = NT / 2;
  constexpr int LA    = 2;                   // loads per A-half (16KB/512thr/16B)
  constexpr int LB    = MODE ? 1 : 2;
  constexpr int BUFE  = (BM + BNT) * BK;     // elems per LDS buffer
  constexpr int AHALF_E = 128 * BK;
  constexpr int BHALF_E = (BNT / 2) * BK;

  // bijective XCD-aware swizzle (m204)
  int nwg = gridDim.x, orig = blockIdx.x;
  int q8 = nwg >> 3, r8 = nwg & 7;
  int xcd = orig & 7, jj0 = orig >> 3;
  int w = (xcd < r8 ? xcd * (q8 + 1) : r8 * (q8 + 1) + (xcd - r8) * q8) + jj0;
  int tn = w % GX;
  int tm = tile_base + w / GX;
  int e = texp[tm];
  if (e < 0) return;

  int tid = threadIdx.x, lane = tid & 63, wid = tid >> 6;
  int wm = MODE ? (wid >> 1) : (wid >> 2);
  int wn = MODE ? (wid & 1) : (wid & 3);
  int lr = lane & 15, kg = lane >> 4;

  __shared__ __align__(16) bf16 lds[2 * BUFE];   // 128KB / 96KB

  const bf16* Bexp = Bt + ((size_t)e * NCOL + (size_t)tn * BNT) * KT;

  // hoisted staging source pointers (source-side swizzle, rule #21)
  const bf16* aptr[2][LA];
  const bf16* bptr[2][LB];
#pragma unroll
  for (int h = 0; h < 2; ++h) {
#pragma unroll
    for (int it = 0; it < LA; ++it) {
      int ch = it * 512 + tid, il = ch >> 3, c = ch & 7;
      int row = h * 128 + il;
      int arow = MODE ? (tm - tile_base) * BM + row : tok[tm * BM + row];
      aptr[h][it] = A + (size_t)arow * KT + (c ^ (il & 7)) * 8;
    }
#pragma unroll
    for (int it = 0; it < LB; ++it) {
      int ch = it * 512 + tid, il = ch >> 3, c = ch & 7;
      int row = h * (BNT / 2) + il;
      bptr[h][it] = Bexp + (size_t)row * KT + (c ^ (il & 7)) * 8;
    }
  }

  auto stageA = [&](int h, int kt) {
    if (kt >= NT) return;
    char* dst = (char*)lds + ((size_t)(kt & 1) * BUFE + h * AHALF_E) * 2;
#pragma unroll
    for (int it = 0; it < LA; ++it)
      gload16(aptr[h][it] + kt * BK, dst + (it * 512 + wid * 64) * 16);
  };
  auto stageB = [&](int h, int kt) {
    if (kt >= NT) return;
    char* dst = (char*)lds + ((size_t)(kt & 1) * BUFE + BM * BK + h * BHALF_E) * 2;
#pragma unroll
    for (int it = 0; it < LB; ++it)
      gload16(bptr[h][it] + kt * BK, dst + (it * 512 + wid * 64) * 16);
  };

  f32x4 acc[MI][4];
#pragma unroll
  for (int i = 0; i < MI; i++)
#pragma unroll
    for (int j = 0; j < 4; j++) acc[i][j] = (f32x4){0.f, 0.f, 0.f, 0.f};

  bf16x8 bv[8];
  auto readB = [&](int buf) {
    const bf16* base = lds + buf * BUFE + BM * BK;
#pragma unroll
    for (int ni = 0; ni < 4; ++ni)
#pragma unroll
      for (int kh = 0; kh < 2; ++kh) {
        int n = wn * 64 + ni * 16 + lr;
        int ph = (kh * 4 + kg) ^ (n & 7);
        bv[ni * 2 + kh] = *(const bf16x8*)&base[n * BK + ph * 8];
      }
  };
  auto readA = [&](int buf, int q, bf16x8* av) {
    const bf16* base = lds + buf * BUFE;
#pragma unroll
    for (int g = 0; g < MPP; ++g)
#pragma unroll
      for (int kh = 0; kh < 2; ++kh) {
        int m = wm * (MI * 16) + (q * MPP + g) * 16 + lr;
        int ph = (kh * 4 + kg) ^ (m & 7);
        av[g * 2 + kh] = *(const bf16x8*)&base[m * BK + ph * 8];
      }
  };
  auto domfma = [&](int q, bf16x8* av) {
    __builtin_amdgcn_s_setprio(1);
#pragma unroll
    for (int g = 0; g < MPP; ++g)
#pragma unroll
      for (int ni = 0; ni < 4; ++ni)
#pragma unroll
        for (int kh = 0; kh < 2; ++kh)
          acc[q * MPP + g][ni] = __builtin_amdgcn_mfma_f32_16x16x32_bf16(
              av[g * 2 + kh], bv[ni * 2 + kh], acc[q * MPP + g][ni], 0, 0, 0);
    __builtin_amdgcn_s_setprio(0);
  };

#define WAIT_VMC() do { if (MODE) asm volatile("s_waitcnt vmcnt(4)" ::: "memory"); \
                        else      asm volatile("s_waitcnt vmcnt(6)" ::: "memory"); } while(0)
#define PH_TAIL()  do { asm volatile("s_waitcnt lgkmcnt(0)" ::: "memory"); \
                        __builtin_amdgcn_sched_barrier(0); } while(0)

  // prologue: B(0), A(0), B(1)
  stageB(0, 0); stageB(1, 0); stageA(0, 0); stageA(1, 0); stageB(0, 1); stageB(1, 1);

#pragma unroll 1
  for (int i = 0; i < NITER; ++i) {
    int kt0 = 2 * i;
    bool last = (i == NITER - 1);
    bf16x8 av[2 * MPP];

    // phase 0 (buf0, q0, head): stage Alo(kt0+1) -> vmcnt -> bar -> reads
    stageA(0, kt0 + 1);
    WAIT_VMC();
    __builtin_amdgcn_s_barrier();
    readB(0);
    readA(0, 0, av);
    PH_TAIL();
    domfma(0, av);
    __builtin_amdgcn_s_barrier();

    // phase 1
    readA(0, 1, av);
    stageA(1, kt0 + 1);
    __builtin_amdgcn_s_barrier();
    PH_TAIL();
    domfma(1, av);
    __builtin_amdgcn_s_barrier();

    // phase 2
    readA(0, 2, av);
    stageB(0, kt0 + 2);
    __builtin_amdgcn_s_barrier();
    PH_TAIL();
    domfma(2, av);
    __builtin_amdgcn_s_barrier();

    // phase 3
    readA(0, 3, av);
    stageB(1, kt0 + 2);
    __builtin_amdgcn_s_barrier();
    PH_TAIL();
    domfma(3, av);
    __builtin_amdgcn_s_barrier();

    // phase 4 (buf1, q0, head): stage Alo(kt0+2) -> vmcnt -> bar -> reads
    stageA(0, kt0 + 2);
    if (last) { asm volatile("s_waitcnt vmcnt(0)" ::: "memory"); }
    else      { WAIT_VMC(); }
    __builtin_amdgcn_s_barrier();
    readB(1);
    readA(1, 0, av);
    PH_TAIL();
    domfma(0, av);
    __builtin_amdgcn_s_barrier();

    // phase 5
    readA(1, 1, av);
    stageA(1, kt0 + 2);
    __builtin_amdgcn_s_barrier();
    PH_TAIL();
    domfma(1, av);
    __builtin_amdgcn_s_barrier();

    // phase 6
    readA(1, 2, av);
    stageB(0, kt0 + 3);
    __builtin_amdgcn_s_barrier();
    PH_TAIL();
    domfma(2, av);
    __builtin_amdgcn_s_barrier();

    // phase 7
    readA(1, 3, av);
    stageB(1, kt0 + 3);
    __builtin_amdgcn_s_barrier();
    PH_TAIL();
    domfma(3, av);
    __builtin_amdgcn_s_barrier();
  }

  // epilogue
  const float* be = bias + (size_t)e * NCOL;
#pragma unroll
  for (int ni = 0; ni < 4; ++ni) {
    int n = tn * BNT + wn * 64 + ni * 16 + lr;
    float bvv = be[n];
#pragma unroll
    for (int mi = 0; mi < MI; ++mi) {
#pragma unroll
      for (int j = 0; j < 4; j++) {
        int mrow = wm * (MI * 16) + mi * 16 + kg * 4 + j;   // C/D map m89
        float v = acc[mi][ni][j] + bvv;
        if (MODE == 0) {
          v = fmaxf(v, 0.f);
          ((bf16*)Cout)[(size_t)((tm - tile_base) * BM + mrow) * NCOL + n] =
              __float2bfloat16(v);
        } else {
          ((bf16*)Cout)[(size_t)(tm * BM + mrow) * NCOL + n] = __float2bfloat16(v);
        }
      }
    }
  }
#undef WAIT_VMC
#undef PH_TAIL
}

// ---- combine (bf16 y) ----
__global__ void k_combine(const bf16* __restrict__ y, const float* __restrict__ prob,
                          const int* __restrict__ pos, float* __restrict__ out) {
  int gid = blockIdx.x * blockDim.x + threadIdx.x;  // over N*D/8
  if (gid >= N_TOK * DDIM / 8) return;
  int n = gid >> 7;          // DDIM/8 = 128
  int d8 = gid & 127;
  int r0 = pos[2 * n], r1 = pos[2 * n + 1];
  float p0 = prob[2 * n], p1 = prob[2 * n + 1];
  uint4 a = *(const uint4*)&y[(size_t)r0 * DDIM + d8 * 8];
  uint4 b = *(const uint4*)&y[(size_t)r1 * DDIM + d8 * 8];
  const unsigned short* ah = (const unsigned short*)&a;
  const unsigned short* bh = (const unsigned short*)&b;
  float o[8];
#pragma unroll
  for (int k = 0; k < 8; k++) {
    float fa = __uint_as_float((unsigned)ah[k] << 16);
    float fb = __uint_as_float((unsigned)bh[k] << 16);
    o[k] = p0 * fa + p1 * fb;
  }
  float4* op = (float4*)&out[(size_t)n * DDIM + d8 * 8];
  op[0] = (float4){o[0], o[1], o[2], o[3]};
  op[1] = (float4){o[4], o[5], o[6], o[7]};
  if (gid == 0) out[(size_t)N_TOK * DDIM] = 0.f;   // total_loss
}

extern "C" void kernel_launch(void* const* d_in, const int* in_sizes, int n_in,
                              void* d_out, int out_size, void* d_ws, size_t ws_size,
                              hipStream_t stream) {
  const float* x    = (const float*)d_in[0];
  const float* prob = (const float*)d_in[1];
  const int*   idx  = (const int*)d_in[2];
  const float* W1   = (const float*)d_in[3];
  const float* b1   = (const float*)d_in[4];
  const float* W2   = (const float*)d_in[5];
  const float* b2   = (const float*)d_in[6];
  float* out = (float*)d_out;

  char* ws = (char*)d_ws;
  size_t cur = 0;
  auto alloc = [&](size_t bytes) -> void* {
    cur = (cur + 255) & ~(size_t)255;
    void* p = ws + cur; cur += bytes; return p;
  };
  int* cnt   = (int*)alloc(NEXP * 4);
  int* offp  = (int*)alloc((NEXP + 1) * 4);
  int* off2  = (int*)alloc(NEXP * 4);
  int* flag  = (int*)alloc(4);
  int* texp  = (int*)alloc(MAXT * 4);
  int* tok   = (int*)alloc((size_t)MAXT * BM * 4);
  int* pos   = (int*)alloc((size_t)NK * 4);
  bf16* Xb   = (bf16*)alloc((size_t)N_TOK * DDIM * 2);
  bf16* W1t  = (bf16*)alloc((size_t)NEXP * HDIM * DDIM * 2);
  bf16* W2t  = (bf16*)alloc((size_t)NEXP * DDIM * HDIM * 2);
  bf16* ybuf = (bf16*)alloc((size_t)MAXT * BM * DDIM * 2);
  cur = (cur + 255) & ~(size_t)255;
  size_t h_off = cur;
  size_t h_avail = ws_size > h_off ? ws_size - h_off : 0;
  long long ts_ll = (long long)(h_avail / ((size_t)BM * HDIM * 2));
  int ts = (int)(ts_ll < 1 ? 1 : (ts_ll > MAXT ? MAXT : ts_ll));
  bf16* hbuf = (bf16*)(ws + h_off);

  hipMemsetAsync(cnt, 0, NEXP * 4, stream);
  k_detect<<<1, 64, 0, stream>>>(idx, flag);
  k_count<<<(NK + 255) / 256, 256, 0, stream>>>(idx, flag, cnt);
  k_scan<<<1, 256, 0, stream>>>(cnt, offp, off2, texp, tok);
  k_scatter<<<(NK + 255) / 256, 256, 0, stream>>>(idx, flag, off2, tok, pos);
  k_cvt_x<<<(N_TOK * DDIM / 8 + 255) / 256, 256, 0, stream>>>(x, Xb);
  k_transpose<<<dim3(HDIM / 32, DDIM / 32, NEXP), 256, 0, stream>>>(W1, W1t, DDIM, HDIM);
  k_transpose<<<dim3(DDIM / 32, HDIM / 32, NEXP), 256, 0, stream>>>(W2, W2t, HDIM, DDIM);

  for (int base = 0; base < MAXT; base += ts) {
    int cnt_t = (MAXT - base < ts) ? (MAXT - base) : ts;
    k_gemm<0><<<dim3((HDIM / 256) * cnt_t), 512, 0, stream>>>(
        Xb, W1t, b1, texp, tok, base, (void*)hbuf);
    k_gemm<1><<<dim3((DDIM / 128) * cnt_t), 512, 0, stream>>>(
        hbuf, W2t, b2, texp, tok, base, (void*)ybuf);
  }
  k_combine<<<(N_TOK * DDIM / 8 + 255) / 256, 256, 0, stream>>>(ybuf, prob, pos, out);
}